// Round 2
// baseline (496.474 us; speedup 1.0000x reference)
//
#include <hip/hip_runtime.h>
#include <hip/hip_bf16.h>

#define NPIX (512 * 512)
#define IMW 512
#define IMH 512

static __device__ __forceinline__ unsigned short f2bf(float f) {
  union { __hip_bfloat16 h; unsigned short u; } cv;
  cv.h = __float2bfloat16(f);  // RNE convert
  return cv.u;
}

static __device__ __forceinline__ float4 bf4_to_f4(ushort4 u) {
  float4 r;
  r.x = __uint_as_float(((unsigned)u.x) << 16);  // bf16->f32 exact
  r.y = __uint_as_float(((unsigned)u.y) << 16);
  r.z = __uint_as_float(((unsigned)u.z) << 16);
  r.w = __uint_as_float(((unsigned)u.w) << 16);
  return r;
}

// ---------------------------------------------------------------------------
// Kernel 1: fused pointwise transforms, thread-per-pixel.
// Design: x[64] is the irreducible live set (every output consumes every
// input channel); outputs stream through 4 accumulators at a time so the
// compiler never faces a >80-reg live range (round-1 version kept acc[64]
// live and got spill-restructured: VGPR_Count=56, 8x slowdown).
//   proj_t  [N][64]  bf16 pixel-major (halves k2's random-gather bytes)
//   flows_t [N][8]   f32
//   wts_t   [N][4]   f32 softmax'd
// ---------------------------------------------------------------------------
__global__ __launch_bounds__(256, 4) void k1_pointwise(
    const float* __restrict__ in, const float* __restrict__ conv_w,
    const float* __restrict__ conv_b, const float* __restrict__ offset_w,
    const float* __restrict__ offset_b, const float* __restrict__ wconv_w,
    const float* __restrict__ wconv_b, __hip_bfloat16* __restrict__ proj_t,
    float* __restrict__ flows_t, float* __restrict__ wts_t) {
  const int n = blockIdx.x * 256 + threadIdx.x;

  float x[64];
#pragma unroll
  for (int c = 0; c < 64; ++c) x[c] = in[(size_t)c * NPIX + n];

  // proj: 16 groups of 4 output channels; weights wave-uniform -> SGPR.
  ushort4* pj = (ushort4*)(proj_t + (size_t)n * 64);
#pragma unroll 1
  for (int g = 0; g < 16; ++g) {
    const float* wrow = conv_w + (size_t)g * 4 * 64;
    float a0 = conv_b[4 * g + 0];
    float a1 = conv_b[4 * g + 1];
    float a2 = conv_b[4 * g + 2];
    float a3 = conv_b[4 * g + 3];
#pragma unroll
    for (int c = 0; c < 64; ++c) {
      const float xc = x[c];
      a0 = fmaf(xc, wrow[c], a0);
      a1 = fmaf(xc, wrow[64 + c], a1);
      a2 = fmaf(xc, wrow[128 + c], a2);
      a3 = fmaf(xc, wrow[192 + c], a3);
    }
    pj[g] = make_ushort4(f2bf(a0), f2bf(a1), f2bf(a2), f2bf(a3));
  }

  // flows: 8 outputs (k*2+d), 2 groups of 4.
  float fa[8];
#pragma unroll 1
  for (int g = 0; g < 2; ++g) {
    const float* wrow = offset_w + (size_t)g * 4 * 64;
    float a0 = offset_b[4 * g + 0];
    float a1 = offset_b[4 * g + 1];
    float a2 = offset_b[4 * g + 2];
    float a3 = offset_b[4 * g + 3];
#pragma unroll
    for (int c = 0; c < 64; ++c) {
      const float xc = x[c];
      a0 = fmaf(xc, wrow[c], a0);
      a1 = fmaf(xc, wrow[64 + c], a1);
      a2 = fmaf(xc, wrow[128 + c], a2);
      a3 = fmaf(xc, wrow[192 + c], a3);
    }
    fa[4 * g + 0] = a0; fa[4 * g + 1] = a1;
    fa[4 * g + 2] = a2; fa[4 * g + 3] = a3;
  }
  float4* fl4 = (float4*)(flows_t + (size_t)n * 8);
  fl4[0] = make_float4(fa[0], fa[1], fa[2], fa[3]);
  fl4[1] = make_float4(fa[4], fa[5], fa[6], fa[7]);

  // weights: 4 outputs + softmax
  {
    float a0 = wconv_b[0], a1 = wconv_b[1], a2 = wconv_b[2], a3 = wconv_b[3];
#pragma unroll
    for (int c = 0; c < 64; ++c) {
      const float xc = x[c];
      a0 = fmaf(xc, wconv_w[c], a0);
      a1 = fmaf(xc, wconv_w[64 + c], a1);
      a2 = fmaf(xc, wconv_w[128 + c], a2);
      a3 = fmaf(xc, wconv_w[192 + c], a3);
    }
    const float m = fmaxf(fmaxf(a0, a1), fmaxf(a2, a3));
    const float e0 = __expf(a0 - m), e1 = __expf(a1 - m);
    const float e2 = __expf(a2 - m), e3 = __expf(a3 - m);
    const float inv = 1.f / (e0 + e1 + e2 + e3);
    *(float4*)(wts_t + (size_t)n * 4) =
        make_float4(e0 * inv, e1 * inv, e2 * inv, e3 * inv);
  }
}

// ---------------------------------------------------------------------------
// Kernel 2: deformable bilinear gather + K-blend.
// 16-lane group per pixel (lane l -> channels 4l..4l+3), bf16 gathers
// (128B contiguous per corner per group), f32 accumulate, LDS transpose
// so each channel's output store is a 256B contiguous run.
// ---------------------------------------------------------------------------
__global__ __launch_bounds__(256) void k2_sample(
    const float* __restrict__ ax, const float* __restrict__ ay,
    const __hip_bfloat16* __restrict__ proj_t,
    const float* __restrict__ flows_t, const float* __restrict__ wts_t,
    float* __restrict__ out) {
  __shared__ float tile[64][68];  // [px][ch]
  const int t = threadIdx.x;
  const int g = t >> 4;   // pixel-group
  const int l = t & 15;   // lane within group: channels 4l..4l+3
  const int p0 = blockIdx.x * 64;

#pragma unroll 1
  for (int pass = 0; pass < 4; ++pass) {
    const int pl = pass * 16 + g;
    const int p = p0 + pl;
    const float axv = ax[p];
    const float ayv = ay[p];
    const int ixi = (int)axv;  // trunc; ax,ay >= 0
    const int iyi = (int)ayv;
    const size_t n2 = (size_t)(iyi * IMW + ixi);
    const float4 f01 = *(const float4*)(flows_t + n2 * 8);
    const float4 f23 = *(const float4*)(flows_t + n2 * 8 + 4);
    const float4 wk4 = *(const float4*)(wts_t + (size_t)p * 4);
    const float fx[4] = {f01.x, f01.z, f23.x, f23.z};
    const float fy[4] = {f01.y, f01.w, f23.y, f23.w};
    const float wk[4] = {wk4.x, wk4.y, wk4.z, wk4.w};

    float4 acc = make_float4(0.f, 0.f, 0.f, 0.f);
#pragma unroll
    for (int k = 0; k < 4; ++k) {
      const float xs = (axv + fx[k]) * (512.f / 511.f) - 0.5f;
      const float ys = (ayv + fy[k]) * (512.f / 511.f) - 0.5f;
      const float x0f = floorf(xs), y0f = floorf(ys);
      const float wx = xs - x0f, wy = ys - y0f;
      const int x0 = (int)x0f, y0 = (int)y0f;
      const int x1 = x0 + 1, y1 = y0 + 1;
      const int cx0 = min(max(x0, 0), IMW - 1);
      const int cx1 = min(max(x1, 0), IMW - 1);
      const int cy0 = min(max(y0, 0), IMH - 1);
      const int cy1 = min(max(y1, 0), IMH - 1);
      const float vx0 = (x0 >= 0 && x0 < IMW) ? 1.f : 0.f;
      const float vx1 = (x1 >= 0 && x1 < IMW) ? 1.f : 0.f;
      const float vy0 = (y0 >= 0 && y0 < IMH) ? 1.f : 0.f;
      const float vy1 = (y1 >= 0 && y1 < IMH) ? 1.f : 0.f;
      const float s00 = wk[k] * (1.f - wx) * (1.f - wy) * vx0 * vy0;
      const float s10 = wk[k] * wx * (1.f - wy) * vx1 * vy0;
      const float s01 = wk[k] * (1.f - wx) * wy * vx0 * vy1;
      const float s11 = wk[k] * wx * wy * vx1 * vy1;

      const ushort4 u00 =
          *(const ushort4*)(proj_t + (size_t)(cy0 * IMW + cx0) * 64 + l * 4);
      const ushort4 u10 =
          *(const ushort4*)(proj_t + (size_t)(cy0 * IMW + cx1) * 64 + l * 4);
      const ushort4 u01 =
          *(const ushort4*)(proj_t + (size_t)(cy1 * IMW + cx0) * 64 + l * 4);
      const ushort4 u11 =
          *(const ushort4*)(proj_t + (size_t)(cy1 * IMW + cx1) * 64 + l * 4);
      const float4 v00 = bf4_to_f4(u00);
      const float4 v10 = bf4_to_f4(u10);
      const float4 v01 = bf4_to_f4(u01);
      const float4 v11 = bf4_to_f4(u11);

      acc.x += s00 * v00.x + s10 * v10.x + s01 * v01.x + s11 * v11.x;
      acc.y += s00 * v00.y + s10 * v10.y + s01 * v01.y + s11 * v11.y;
      acc.z += s00 * v00.z + s10 * v10.z + s01 * v01.z + s11 * v11.z;
      acc.w += s00 * v00.w + s10 * v10.w + s01 * v01.w + s11 * v11.w;
    }
    *(float4*)&tile[pl][4 * l] = acc;
  }
  __syncthreads();

  // Transpose-store: 16 channels x 16 pixel-quads per iter.
#pragma unroll
  for (int it = 0; it < 4; ++it) {
    const int c = it * 16 + g;
    float4 vv;
    vv.x = tile[4 * l + 0][c];
    vv.y = tile[4 * l + 1][c];
    vv.z = tile[4 * l + 2][c];
    vv.w = tile[4 * l + 3][c];
    *(float4*)(out + (size_t)c * NPIX + p0 + 4 * l) = vv;
  }
}

extern "C" void kernel_launch(void* const* d_in, const int* in_sizes, int n_in,
                              void* d_out, int out_size, void* d_ws,
                              size_t ws_size, hipStream_t stream) {
  const float* input = (const float*)d_in[0];
  const float* ax = (const float*)d_in[1];
  const float* ay = (const float*)d_in[2];
  const float* conv_w = (const float*)d_in[3];
  const float* conv_b = (const float*)d_in[4];
  const float* offset_w = (const float*)d_in[5];
  const float* offset_b = (const float*)d_in[6];
  const float* wconv_w = (const float*)d_in[7];
  const float* wconv_b = (const float*)d_in[8];
  float* out = (float*)d_out;

  __hip_bfloat16* proj_t = (__hip_bfloat16*)d_ws;          // 32 MiB
  float* flows_t = (float*)(proj_t + (size_t)NPIX * 64);   // 8 MiB
  float* wts_t = flows_t + (size_t)NPIX * 8;               // 4 MiB

  hipLaunchKernelGGL(k1_pointwise, dim3(NPIX / 256), dim3(256), 0, stream,
                     input, conv_w, conv_b, offset_w, offset_b, wconv_w,
                     wconv_b, proj_t, flows_t, wts_t);
  hipLaunchKernelGGL(k2_sample, dim3(NPIX / 64), dim3(256), 0, stream, ax, ay,
                     proj_t, flows_t, wts_t, out);
}

// Round 3
// 295.282 us; speedup vs baseline: 1.6814x; 1.6814x over previous
//
#include <hip/hip_runtime.h>
#include <hip/hip_bf16.h>

#define NPIX (512 * 512)
#define IMW 512
#define IMH 512

static __device__ __forceinline__ unsigned short f2bf(float f) {
  union { __hip_bfloat16 h; unsigned short u; } cv;
  cv.h = __float2bfloat16(f);  // RNE convert
  return cv.u;
}

// ---------------------------------------------------------------------------
// Kernel 1: fused pointwise transforms, thread-per-pixel.
// x[64] (the irreducible live set) stays in VGPRs; the 76 outputs stream
// through 4 accumulators at a time; weight loads are wave-uniform -> scalar.
// amdgpu_waves_per_eu(2,4): round-2 showed the allocator capping at 64 VGPRs
// (8 waves/EU target) and spilling x[] to scratch (FETCH 33->744 MB, 2.7x
// slowdown). Capping occupancy at 4 waves/EU removes the incentive to
// allocate below 128 regs; min 2 keeps a 256-reg hard ceiling.
// ---------------------------------------------------------------------------
__global__ __launch_bounds__(256)
__attribute__((amdgpu_waves_per_eu(2, 4))) void k1_pointwise(
    const float* __restrict__ in, const float* __restrict__ conv_w,
    const float* __restrict__ conv_b, const float* __restrict__ offset_w,
    const float* __restrict__ offset_b, const float* __restrict__ wconv_w,
    const float* __restrict__ wconv_b, __hip_bfloat16* __restrict__ proj_t,
    float* __restrict__ flows_t, float* __restrict__ wts_t) {
  const int n = blockIdx.x * 256 + threadIdx.x;

  float x[64];
#pragma unroll
  for (int c = 0; c < 64; ++c) x[c] = in[(size_t)c * NPIX + n];

  // proj: 16 groups of 4 output channels.
  ushort4* pj = (ushort4*)(proj_t + (size_t)n * 64);
#pragma unroll 1
  for (int g = 0; g < 16; ++g) {
    const float* wrow = conv_w + (size_t)g * 4 * 64;
    float a0 = conv_b[4 * g + 0];
    float a1 = conv_b[4 * g + 1];
    float a2 = conv_b[4 * g + 2];
    float a3 = conv_b[4 * g + 3];
#pragma unroll
    for (int c = 0; c < 64; ++c) {
      const float xc = x[c];
      a0 = fmaf(xc, wrow[c], a0);
      a1 = fmaf(xc, wrow[64 + c], a1);
      a2 = fmaf(xc, wrow[128 + c], a2);
      a3 = fmaf(xc, wrow[192 + c], a3);
    }
    pj[g] = make_ushort4(f2bf(a0), f2bf(a1), f2bf(a2), f2bf(a3));
  }

  // flows: 8 outputs, 2 groups of 4.
  float fa[8];
#pragma unroll 1
  for (int g = 0; g < 2; ++g) {
    const float* wrow = offset_w + (size_t)g * 4 * 64;
    float a0 = offset_b[4 * g + 0];
    float a1 = offset_b[4 * g + 1];
    float a2 = offset_b[4 * g + 2];
    float a3 = offset_b[4 * g + 3];
#pragma unroll
    for (int c = 0; c < 64; ++c) {
      const float xc = x[c];
      a0 = fmaf(xc, wrow[c], a0);
      a1 = fmaf(xc, wrow[64 + c], a1);
      a2 = fmaf(xc, wrow[128 + c], a2);
      a3 = fmaf(xc, wrow[192 + c], a3);
    }
    fa[4 * g + 0] = a0; fa[4 * g + 1] = a1;
    fa[4 * g + 2] = a2; fa[4 * g + 3] = a3;
  }
  float4* fl4 = (float4*)(flows_t + (size_t)n * 8);
  fl4[0] = make_float4(fa[0], fa[1], fa[2], fa[3]);
  fl4[1] = make_float4(fa[4], fa[5], fa[6], fa[7]);

  // weights: 4 outputs + softmax over K=4.
  {
    float a0 = wconv_b[0], a1 = wconv_b[1], a2 = wconv_b[2], a3 = wconv_b[3];
#pragma unroll
    for (int c = 0; c < 64; ++c) {
      const float xc = x[c];
      a0 = fmaf(xc, wconv_w[c], a0);
      a1 = fmaf(xc, wconv_w[64 + c], a1);
      a2 = fmaf(xc, wconv_w[128 + c], a2);
      a3 = fmaf(xc, wconv_w[192 + c], a3);
    }
    const float m = fmaxf(fmaxf(a0, a1), fmaxf(a2, a3));
    const float e0 = __expf(a0 - m), e1 = __expf(a1 - m);
    const float e2 = __expf(a2 - m), e3 = __expf(a3 - m);
    const float inv = 1.f / (e0 + e1 + e2 + e3);
    *(float4*)(wts_t + (size_t)n * 4) =
        make_float4(e0 * inv, e1 * inv, e2 * inv, e3 * inv);
  }
}

// ---------------------------------------------------------------------------
// Kernel 2: deformable bilinear gather + K-blend.
// 8-lane group per pixel, lane owns 8 channels -> one uint4 (8 bf16, 16B)
// per corner. Round-2 lesson: halving gather BYTES didn't move k2 (latency/
// issue-bound, VALUBusy 24%); this halves gather INSTRUCTIONS per pixel and
// doubles bytes-in-flight per request (256B/corner). bf16 unpack is exact
// bit-shifts. LDS transpose so each output-channel store is a 256B run.
// ---------------------------------------------------------------------------
__global__ __launch_bounds__(256) void k2_sample(
    const float* __restrict__ ax, const float* __restrict__ ay,
    const __hip_bfloat16* __restrict__ proj_t,
    const float* __restrict__ flows_t, const float* __restrict__ wts_t,
    float* __restrict__ out) {
  __shared__ float tile[64][68];  // [px][ch]
  const int t = threadIdx.x;
  const int g8 = t >> 3;  // pixel-group (0..31)
  const int l8 = t & 7;   // lane within group: channels 8*l8 .. 8*l8+7
  const int p0 = blockIdx.x * 64;

#pragma unroll 1
  for (int pass = 0; pass < 2; ++pass) {
    const int pl = pass * 32 + g8;
    const int p = p0 + pl;
    const float axv = ax[p];
    const float ayv = ay[p];
    const int ixi = (int)axv;  // trunc; ax,ay >= 0
    const int iyi = (int)ayv;
    const size_t n2 = (size_t)(iyi * IMW + ixi);
    const float4 f01 = *(const float4*)(flows_t + n2 * 8);
    const float4 f23 = *(const float4*)(flows_t + n2 * 8 + 4);
    const float4 wk4 = *(const float4*)(wts_t + (size_t)p * 4);
    const float fx[4] = {f01.x, f01.z, f23.x, f23.z};
    const float fy[4] = {f01.y, f01.w, f23.y, f23.w};
    const float wk[4] = {wk4.x, wk4.y, wk4.z, wk4.w};

    float acc[8];
#pragma unroll
    for (int j = 0; j < 8; ++j) acc[j] = 0.f;

#pragma unroll
    for (int k = 0; k < 4; ++k) {
      const float xs = (axv + fx[k]) * (512.f / 511.f) - 0.5f;
      const float ys = (ayv + fy[k]) * (512.f / 511.f) - 0.5f;
      const float x0f = floorf(xs), y0f = floorf(ys);
      const float wx = xs - x0f, wy = ys - y0f;
      const int x0 = (int)x0f, y0 = (int)y0f;
      const int x1 = x0 + 1, y1 = y0 + 1;
      const int cx0 = min(max(x0, 0), IMW - 1);
      const int cx1 = min(max(x1, 0), IMW - 1);
      const int cy0 = min(max(y0, 0), IMH - 1);
      const int cy1 = min(max(y1, 0), IMH - 1);
      const float vx0 = (x0 >= 0 && x0 < IMW) ? 1.f : 0.f;
      const float vx1 = (x1 >= 0 && x1 < IMW) ? 1.f : 0.f;
      const float vy0 = (y0 >= 0 && y0 < IMH) ? 1.f : 0.f;
      const float vy1 = (y1 >= 0 && y1 < IMH) ? 1.f : 0.f;
      const float s00 = wk[k] * (1.f - wx) * (1.f - wy) * vx0 * vy0;
      const float s10 = wk[k] * wx * (1.f - wy) * vx1 * vy0;
      const float s01 = wk[k] * (1.f - wx) * wy * vx0 * vy1;
      const float s11 = wk[k] * wx * wy * vx1 * vy1;

      const uint4 u00 = *(const uint4*)(proj_t + (size_t)(cy0 * IMW + cx0) * 64 + l8 * 8);
      const uint4 u10 = *(const uint4*)(proj_t + (size_t)(cy0 * IMW + cx1) * 64 + l8 * 8);
      const uint4 u01 = *(const uint4*)(proj_t + (size_t)(cy1 * IMW + cx0) * 64 + l8 * 8);
      const uint4 u11 = *(const uint4*)(proj_t + (size_t)(cy1 * IMW + cx1) * 64 + l8 * 8);

      const unsigned w00[4] = {u00.x, u00.y, u00.z, u00.w};
      const unsigned w10[4] = {u10.x, u10.y, u10.z, u10.w};
      const unsigned w01[4] = {u01.x, u01.y, u01.z, u01.w};
      const unsigned w11[4] = {u11.x, u11.y, u11.z, u11.w};
#pragma unroll
      for (int q = 0; q < 4; ++q) {
        // word q holds channels 2q (low ushort) and 2q+1 (high ushort)
        acc[2 * q] = fmaf(__uint_as_float(w00[q] << 16), s00, acc[2 * q]);
        acc[2 * q] = fmaf(__uint_as_float(w10[q] << 16), s10, acc[2 * q]);
        acc[2 * q] = fmaf(__uint_as_float(w01[q] << 16), s01, acc[2 * q]);
        acc[2 * q] = fmaf(__uint_as_float(w11[q] << 16), s11, acc[2 * q]);
        acc[2 * q + 1] = fmaf(__uint_as_float(w00[q] & 0xffff0000u), s00, acc[2 * q + 1]);
        acc[2 * q + 1] = fmaf(__uint_as_float(w10[q] & 0xffff0000u), s10, acc[2 * q + 1]);
        acc[2 * q + 1] = fmaf(__uint_as_float(w01[q] & 0xffff0000u), s01, acc[2 * q + 1]);
        acc[2 * q + 1] = fmaf(__uint_as_float(w11[q] & 0xffff0000u), s11, acc[2 * q + 1]);
      }
    }
    *(float4*)&tile[pl][8 * l8] = make_float4(acc[0], acc[1], acc[2], acc[3]);
    *(float4*)&tile[pl][8 * l8 + 4] = make_float4(acc[4], acc[5], acc[6], acc[7]);
  }
  __syncthreads();

  // Transpose-store: 16 channels x 16 pixel-quads per iter.
  const int g16 = t >> 4;
  const int l16 = t & 15;
#pragma unroll
  for (int it = 0; it < 4; ++it) {
    const int c = it * 16 + g16;
    float4 vv;
    vv.x = tile[4 * l16 + 0][c];
    vv.y = tile[4 * l16 + 1][c];
    vv.z = tile[4 * l16 + 2][c];
    vv.w = tile[4 * l16 + 3][c];
    *(float4*)(out + (size_t)c * NPIX + p0 + 4 * l16) = vv;
  }
}

extern "C" void kernel_launch(void* const* d_in, const int* in_sizes, int n_in,
                              void* d_out, int out_size, void* d_ws,
                              size_t ws_size, hipStream_t stream) {
  const float* input = (const float*)d_in[0];
  const float* ax = (const float*)d_in[1];
  const float* ay = (const float*)d_in[2];
  const float* conv_w = (const float*)d_in[3];
  const float* conv_b = (const float*)d_in[4];
  const float* offset_w = (const float*)d_in[5];
  const float* offset_b = (const float*)d_in[6];
  const float* wconv_w = (const float*)d_in[7];
  const float* wconv_b = (const float*)d_in[8];
  float* out = (float*)d_out;

  __hip_bfloat16* proj_t = (__hip_bfloat16*)d_ws;          // 32 MiB
  float* flows_t = (float*)(proj_t + (size_t)NPIX * 64);   // 8 MiB
  float* wts_t = flows_t + (size_t)NPIX * 8;               // 4 MiB

  hipLaunchKernelGGL(k1_pointwise, dim3(NPIX / 256), dim3(256), 0, stream,
                     input, conv_w, conv_b, offset_w, offset_b, wconv_w,
                     wconv_b, proj_t, flows_t, wts_t);
  hipLaunchKernelGGL(k2_sample, dim3(NPIX / 64), dim3(256), 0, stream, ax, ay,
                     proj_t, flows_t, wts_t, out);
}

// Round 4
// 247.603 us; speedup vs baseline: 2.0051x; 1.1926x over previous
//
#include <hip/hip_runtime.h>
#include <hip/hip_bf16.h>

#define NPIX (512 * 512)
#define IMW 512
#define IMH 512

typedef float fvec4 __attribute__((ext_vector_type(4)));

static __device__ __forceinline__ unsigned short f2bf(float f) {
  union { __hip_bfloat16 h; unsigned short u; } cv;
  cv.h = __float2bfloat16(f);  // RNE convert
  return cv.u;
}

static __device__ __forceinline__ unsigned pack2bf(float lo, float hi) {
  return (unsigned)f2bf(lo) | ((unsigned)f2bf(hi) << 16);
}

// ---------------------------------------------------------------------------
// Kernel 1: fused pointwise transforms, thread-per-pixel, THREE PASSES.
// Rounds 2-3 post-mortem: any formulation keeping x[64] live gets the array
// demoted to scratch (r3: VGPR=80, WRITE 260MB = 1M threads x 256B scratch
// drain; r2: FETCH 744MB = scratch reads missing L2). Instead each pass keeps
// only acc[<=32]+x[8] live (~55 regs) and re-reads the input; passes 2-3 hit
// L2/L3 (input is resident after pass 1). Each proj chunk store is 64B/lane
// contiguous -> full sectors.
// ---------------------------------------------------------------------------
__global__ __launch_bounds__(256) void k1_pointwise(
    const float* __restrict__ in, const float* __restrict__ conv_w,
    const float* __restrict__ conv_b, const float* __restrict__ offset_w,
    const float* __restrict__ offset_b, const float* __restrict__ wconv_w,
    const float* __restrict__ wconv_b, __hip_bfloat16* __restrict__ proj_t,
    float* __restrict__ flows_t, float* __restrict__ wts_t) {
  const int n = blockIdx.x * 256 + threadIdx.x;

  // ---- passes A,B: proj output channels [32*half, 32*half+32) ----
#pragma unroll 1
  for (int half = 0; half < 2; ++half) {
    const float* wbase = conv_w + half * 32 * 64;
    const float* bbase = conv_b + half * 32;
    float acc[32];
#pragma unroll
    for (int o = 0; o < 32; ++o) acc[o] = bbase[o];
#pragma unroll 1
    for (int cb = 0; cb < 64; cb += 8) {
      float x[8];
#pragma unroll
      for (int j = 0; j < 8; ++j) x[j] = in[(size_t)(cb + j) * NPIX + n];
#pragma unroll
      for (int o = 0; o < 32; ++o) {
#pragma unroll
        for (int j = 0; j < 8; ++j)
          acc[o] = fmaf(x[j], wbase[o * 64 + cb + j], acc[o]);
      }
    }
    uint4* pj = (uint4*)(proj_t + (size_t)n * 64 + half * 32);
    uint4 v0, v1, v2, v3;
    v0.x = pack2bf(acc[0], acc[1]);   v0.y = pack2bf(acc[2], acc[3]);
    v0.z = pack2bf(acc[4], acc[5]);   v0.w = pack2bf(acc[6], acc[7]);
    v1.x = pack2bf(acc[8], acc[9]);   v1.y = pack2bf(acc[10], acc[11]);
    v1.z = pack2bf(acc[12], acc[13]); v1.w = pack2bf(acc[14], acc[15]);
    v2.x = pack2bf(acc[16], acc[17]); v2.y = pack2bf(acc[18], acc[19]);
    v2.z = pack2bf(acc[20], acc[21]); v2.w = pack2bf(acc[22], acc[23]);
    v3.x = pack2bf(acc[24], acc[25]); v3.y = pack2bf(acc[26], acc[27]);
    v3.z = pack2bf(acc[28], acc[29]); v3.w = pack2bf(acc[30], acc[31]);
    pj[0] = v0; pj[1] = v1; pj[2] = v2; pj[3] = v3;
  }

  // ---- pass C: flows (8 outputs) + weight logits (4) + softmax ----
  {
    float acc[12];
#pragma unroll
    for (int o = 0; o < 8; ++o) acc[o] = offset_b[o];
#pragma unroll
    for (int o = 0; o < 4; ++o) acc[8 + o] = wconv_b[o];
#pragma unroll 1
    for (int cb = 0; cb < 64; cb += 8) {
      float x[8];
#pragma unroll
      for (int j = 0; j < 8; ++j) x[j] = in[(size_t)(cb + j) * NPIX + n];
#pragma unroll
      for (int o = 0; o < 8; ++o) {
#pragma unroll
        for (int j = 0; j < 8; ++j)
          acc[o] = fmaf(x[j], offset_w[o * 64 + cb + j], acc[o]);
      }
#pragma unroll
      for (int o = 0; o < 4; ++o) {
#pragma unroll
        for (int j = 0; j < 8; ++j)
          acc[8 + o] = fmaf(x[j], wconv_w[o * 64 + cb + j], acc[8 + o]);
      }
    }
    float4* fl4 = (float4*)(flows_t + (size_t)n * 8);
    fl4[0] = make_float4(acc[0], acc[1], acc[2], acc[3]);
    fl4[1] = make_float4(acc[4], acc[5], acc[6], acc[7]);

    const float m = fmaxf(fmaxf(acc[8], acc[9]), fmaxf(acc[10], acc[11]));
    const float e0 = __expf(acc[8] - m), e1 = __expf(acc[9] - m);
    const float e2 = __expf(acc[10] - m), e3 = __expf(acc[11] - m);
    const float inv = 1.f / (e0 + e1 + e2 + e3);
    *(float4*)(wts_t + (size_t)n * 4) =
        make_float4(e0 * inv, e1 * inv, e2 * inv, e3 * inv);
  }
}

// ---------------------------------------------------------------------------
// Kernel 2: deformable bilinear gather + K-blend.
// 8-lane group per pixel, lane owns 8 channels (one uint4 = 8 bf16 per
// corner). This round: both passes' ax/ay/wts loads and BOTH flow gathers
// are issued up front (breaks the ax->flows->corners serial latency chain),
// and output stores are nontemporal so the streamed 64MB output doesn't
// evict proj from L2 (proj reuse is what holds gather HBM traffic down).
// ---------------------------------------------------------------------------
static __device__ __forceinline__ void sample_one(
    float axv, float ayv, float4 f01, float4 f23, float4 wk4,
    const __hip_bfloat16* __restrict__ proj_t, int l8,
    float* __restrict__ dst) {
  const float fx[4] = {f01.x, f01.z, f23.x, f23.z};
  const float fy[4] = {f01.y, f01.w, f23.y, f23.w};
  const float wk[4] = {wk4.x, wk4.y, wk4.z, wk4.w};

  float acc[8];
#pragma unroll
  for (int j = 0; j < 8; ++j) acc[j] = 0.f;

#pragma unroll
  for (int k = 0; k < 4; ++k) {
    const float xs = (axv + fx[k]) * (512.f / 511.f) - 0.5f;
    const float ys = (ayv + fy[k]) * (512.f / 511.f) - 0.5f;
    const float x0f = floorf(xs), y0f = floorf(ys);
    const float wx = xs - x0f, wy = ys - y0f;
    const int x0 = (int)x0f, y0 = (int)y0f;
    const int x1 = x0 + 1, y1 = y0 + 1;
    const int cx0 = min(max(x0, 0), IMW - 1);
    const int cx1 = min(max(x1, 0), IMW - 1);
    const int cy0 = min(max(y0, 0), IMH - 1);
    const int cy1 = min(max(y1, 0), IMH - 1);
    const float vx0 = (x0 >= 0 && x0 < IMW) ? 1.f : 0.f;
    const float vx1 = (x1 >= 0 && x1 < IMW) ? 1.f : 0.f;
    const float vy0 = (y0 >= 0 && y0 < IMH) ? 1.f : 0.f;
    const float vy1 = (y1 >= 0 && y1 < IMH) ? 1.f : 0.f;
    const float s00 = wk[k] * (1.f - wx) * (1.f - wy) * vx0 * vy0;
    const float s10 = wk[k] * wx * (1.f - wy) * vx1 * vy0;
    const float s01 = wk[k] * (1.f - wx) * wy * vx0 * vy1;
    const float s11 = wk[k] * wx * wy * vx1 * vy1;

    const uint4 u00 = *(const uint4*)(proj_t + (size_t)(cy0 * IMW + cx0) * 64 + l8 * 8);
    const uint4 u10 = *(const uint4*)(proj_t + (size_t)(cy0 * IMW + cx1) * 64 + l8 * 8);
    const uint4 u01 = *(const uint4*)(proj_t + (size_t)(cy1 * IMW + cx0) * 64 + l8 * 8);
    const uint4 u11 = *(const uint4*)(proj_t + (size_t)(cy1 * IMW + cx1) * 64 + l8 * 8);

    const unsigned w00[4] = {u00.x, u00.y, u00.z, u00.w};
    const unsigned w10[4] = {u10.x, u10.y, u10.z, u10.w};
    const unsigned w01[4] = {u01.x, u01.y, u01.z, u01.w};
    const unsigned w11[4] = {u11.x, u11.y, u11.z, u11.w};
#pragma unroll
    for (int q = 0; q < 4; ++q) {
      acc[2 * q] = fmaf(__uint_as_float(w00[q] << 16), s00, acc[2 * q]);
      acc[2 * q] = fmaf(__uint_as_float(w10[q] << 16), s10, acc[2 * q]);
      acc[2 * q] = fmaf(__uint_as_float(w01[q] << 16), s01, acc[2 * q]);
      acc[2 * q] = fmaf(__uint_as_float(w11[q] << 16), s11, acc[2 * q]);
      acc[2 * q + 1] = fmaf(__uint_as_float(w00[q] & 0xffff0000u), s00, acc[2 * q + 1]);
      acc[2 * q + 1] = fmaf(__uint_as_float(w10[q] & 0xffff0000u), s10, acc[2 * q + 1]);
      acc[2 * q + 1] = fmaf(__uint_as_float(w01[q] & 0xffff0000u), s01, acc[2 * q + 1]);
      acc[2 * q + 1] = fmaf(__uint_as_float(w11[q] & 0xffff0000u), s11, acc[2 * q + 1]);
    }
  }
  *(float4*)(dst) = make_float4(acc[0], acc[1], acc[2], acc[3]);
  *(float4*)(dst + 4) = make_float4(acc[4], acc[5], acc[6], acc[7]);
}

__global__ __launch_bounds__(256) void k2_sample(
    const float* __restrict__ ax, const float* __restrict__ ay,
    const __hip_bfloat16* __restrict__ proj_t,
    const float* __restrict__ flows_t, const float* __restrict__ wts_t,
    float* __restrict__ out) {
  __shared__ float tile[64][68];  // [px][ch]
  const int t = threadIdx.x;
  const int g8 = t >> 3;  // pixel within half-tile (0..31)
  const int l8 = t & 7;   // lane within group: channels 8*l8 .. 8*l8+7
  const int p0 = blockIdx.x * 64;
  const int pA = p0 + g8;
  const int pB = p0 + 32 + g8;

  // Hoisted loads: sequential ax/ay/wts for both halves, then both flow
  // gathers in flight before any corner work.
  const float axA = ax[pA], ayA = ay[pA];
  const float axB = ax[pB], ayB = ay[pB];
  const float4 wkA = *(const float4*)(wts_t + (size_t)pA * 4);
  const float4 wkB = *(const float4*)(wts_t + (size_t)pB * 4);
  const size_t nA = (size_t)((int)ayA * IMW + (int)axA);  // trunc, ax,ay>=0
  const size_t nB = (size_t)((int)ayB * IMW + (int)axB);
  const float4 fA01 = *(const float4*)(flows_t + nA * 8);
  const float4 fA23 = *(const float4*)(flows_t + nA * 8 + 4);
  const float4 fB01 = *(const float4*)(flows_t + nB * 8);
  const float4 fB23 = *(const float4*)(flows_t + nB * 8 + 4);

  sample_one(axA, ayA, fA01, fA23, wkA, proj_t, l8, &tile[g8][8 * l8]);
  sample_one(axB, ayB, fB01, fB23, wkB, proj_t, l8, &tile[32 + g8][8 * l8]);
  __syncthreads();

  // Transpose-store: each output-channel row is a 256B contiguous run.
  const int g16 = t >> 4;
  const int l16 = t & 15;
#pragma unroll
  for (int it = 0; it < 4; ++it) {
    const int c = it * 16 + g16;
    fvec4 vv;
    vv.x = tile[4 * l16 + 0][c];
    vv.y = tile[4 * l16 + 1][c];
    vv.z = tile[4 * l16 + 2][c];
    vv.w = tile[4 * l16 + 3][c];
    __builtin_nontemporal_store(
        vv, (fvec4*)(out + (size_t)c * NPIX + p0 + 4 * l16));
  }
}

extern "C" void kernel_launch(void* const* d_in, const int* in_sizes, int n_in,
                              void* d_out, int out_size, void* d_ws,
                              size_t ws_size, hipStream_t stream) {
  const float* input = (const float*)d_in[0];
  const float* ax = (const float*)d_in[1];
  const float* ay = (const float*)d_in[2];
  const float* conv_w = (const float*)d_in[3];
  const float* conv_b = (const float*)d_in[4];
  const float* offset_w = (const float*)d_in[5];
  const float* offset_b = (const float*)d_in[6];
  const float* wconv_w = (const float*)d_in[7];
  const float* wconv_b = (const float*)d_in[8];
  float* out = (float*)d_out;

  __hip_bfloat16* proj_t = (__hip_bfloat16*)d_ws;          // 32 MiB
  float* flows_t = (float*)(proj_t + (size_t)NPIX * 64);   // 8 MiB
  float* wts_t = flows_t + (size_t)NPIX * 8;               // 4 MiB

  hipLaunchKernelGGL(k1_pointwise, dim3(NPIX / 256), dim3(256), 0, stream,
                     input, conv_w, conv_b, offset_w, offset_b, wconv_w,
                     wconv_b, proj_t, flows_t, wts_t);
  hipLaunchKernelGGL(k2_sample, dim3(NPIX / 64), dim3(256), 0, stream, ax, ay,
                     proj_t, flows_t, wts_t, out);
}